// Round 5
// baseline (528.050 us; speedup 1.0000x reference)
//
#include <hip/hip_runtime.h>

typedef _Float16 f16;
typedef _Float16 f16x4 __attribute__((ext_vector_type(4)));
typedef _Float16 f16x8 __attribute__((ext_vector_type(8)));
typedef float f32x4 __attribute__((ext_vector_type(4)));

#define EMB 1024
#define SEQL 4096
#define BATCH 4
#define NH 16
#define HD 64
#define BH 64           // BATCH*NH
#define MROWS 16384     // BATCH*SEQL
#define KVSPLIT 16      // l-chunks for split-K kv

#define GLOAD_LDS(gp, lp) \
    __builtin_amdgcn_global_load_lds((const __attribute__((address_space(1))) void*)(gp), \
                                     (__attribute__((address_space(3))) void*)(lp), 16, 0, 0)

// s_waitcnt immediates (gfx9 encoding): vmcnt[3:0]|exp[6:4]|lgkm[11:8]|vmcnt[15:14]
#define WAIT_VM0   0x0F70   // vmcnt(0), lgkm/exp unconstrained
#define WAIT_LGKM0 0xC07F   // lgkmcnt(0), vm/exp unconstrained

// ---------------- fp32 -> fp16 convert ----------------
__global__ void cvt_kernel(const float* __restrict__ in, f16* __restrict__ out, int n4) {
    int i = blockIdx.x * blockDim.x + threadIdx.x;
    if (i < n4) {
        float4 v = ((const float4*)in)[i];
        f16x4 o = { (f16)v.x, (f16)v.y, (f16)v.z, (f16)v.w };
        ((f16x4*)out)[i] = o;
    }
}

struct WPtrs { const float* p[5]; };

__global__ void cvt_w_kernel(WPtrs wp, f16* __restrict__ out) {
    int i = blockIdx.x * blockDim.x + threadIdx.x;
    int wsel = blockIdx.y;
    const float4* src = (const float4*)wp.p[wsel];
    float4 v = src[i];
    f16x4 o = { (f16)v.x, (f16)v.y, (f16)v.z, (f16)v.w };
    ((f16x4*)(out + (size_t)wsel * EMB * EMB))[i] = o;
}

__global__ void zero_kernel(float4* __restrict__ p, int n4) {
    int i = blockIdx.x * blockDim.x + threadIdx.x;
    if (i < n4) p[i] = float4{0.f, 0.f, 0.f, 0.f};
}

// ---------------- barrier-free wave-private MFMA GEMM ----------------
// Each wave owns a 64x64 C-tile; stages its own 64x32 A/B tiles into wave-private LDS
// (no __syncthreads anywhere). Within-wave pipeline:
//   vmcnt(0) -> ds_read frags -> lgkmcnt(0) -> global_load_lds(next k) -> 16 MFMA
// XOR chunk swizzle (phys chunk = logical ^ ((row>>1)&3)) keeps reads 2-way/free.
// MODE 0: Wo GEMM, fp32 row-major out, grid 128m x 8n (lin = m*8+n)
// MODE 1: merged projections x @ [Wq;Wu;Wk;Wv]^T, grid 128m x 32n (lin = m*32+n):
//         n<2048 -> q|u (relu/8, silu) into (b,h,l,hd); n>=2048 -> kT|vT (relu/8, id)
//         into (b,h,hd,l) via swapped MFMA operand order (regs run along l).
template<int MODE>
__global__ __launch_bounds__(256) void gemmw_kernel(
    const f16* __restrict__ A, const f16* __restrict__ Bt,
    void* __restrict__ C0, void* __restrict__ Ckv, int M, int N, int K)
{
    __shared__ f16 SA[4 * 2048];
    __shared__ f16 SB[4 * 2048];

    const int lane = threadIdx.x & 63;
    const int w    = threadIdx.x >> 6;
    const int rw   = lane & 15;
    const int quad = lane >> 4;

    const int nb  = (MODE == 1) ? 32 : 8;
    const int lin = blockIdx.x;
    const int m0  = (lin / nb) * 128;
    const int n0  = (lin % nb) * 128;
    const int mw  = (w >> 1) * 64;
    const int nw  = (w & 1) * 64;
    const bool kvhalf = (MODE == 1) && ((n0 + nw) >= 2048);

    // staging map: lane -> row srow=lane>>2 (within 16-row group), phys chunk lane&3;
    // phys chunk p holds logical chunk p ^ ((srow>>1)&3)
    const int srow = lane >> 2;
    const int scol = (((lane & 3) ^ ((lane >> 3) & 3)) * 8);
    const f16* a_src = A  + (size_t)(m0 + mw + srow) * K + scol;
    const f16* b_src = Bt + (size_t)(n0 + nw + srow) * K + scol;
    f16* lA = &SA[w * 2048];
    f16* lB = &SB[w * 2048];

    // fragment read: logical chunk `quad` of row r at phys quad ^ ((r>>1)&3); r=16i+rw
    const int swz = (quad ^ ((rw >> 1) & 3)) * 8;

    auto stage = [&](int k0) {
        #pragma unroll
        for (int g = 0; g < 4; g++)
            GLOAD_LDS(a_src + (size_t)(g * 16) * K + k0, lA + g * 512);
        #pragma unroll
        for (int g = 0; g < 4; g++)
            GLOAD_LDS(b_src + (size_t)(g * 16) * K + k0, lB + g * 512);
    };

    f32x4 acc[4][4] = {};
    stage(0);

    for (int k0 = 0; k0 < K; k0 += 32) {
        __builtin_amdgcn_s_waitcnt(WAIT_VM0);      // staged tile resident
        f16x8 af[4], bf[4];
        #pragma unroll
        for (int i = 0; i < 4; i++)
            af[i] = *(const f16x8*)&lA[(16 * i + rw) * 32 + swz];
        #pragma unroll
        for (int j = 0; j < 4; j++)
            bf[j] = *(const f16x8*)&lB[(16 * j + rw) * 32 + swz];
        __builtin_amdgcn_s_waitcnt(WAIT_LGKM0);    // frags in regs; LDS reusable
        if (k0 + 32 < K) stage(k0 + 32);           // next tile flies during MFMAs

        if (kvhalf) {
            #pragma unroll
            for (int i = 0; i < 4; i++)
                #pragma unroll
                for (int j = 0; j < 4; j++)
                    acc[i][j] = __builtin_amdgcn_mfma_f32_16x16x32_f16(af[i], bf[j], acc[i][j], 0, 0, 0);
        } else {
            #pragma unroll
            for (int i = 0; i < 4; i++)
                #pragma unroll
                for (int j = 0; j < 4; j++)
                    acc[i][j] = __builtin_amdgcn_mfma_f32_16x16x32_f16(bf[j], af[i], acc[i][j], 0, 0, 0);
        }
    }

    if (MODE == 0) {
        // lane -> m = +rw; regs -> 4 consecutive n
        #pragma unroll
        for (int i = 0; i < 4; i++)
            #pragma unroll
            for (int j = 0; j < 4; j++) {
                const int m_idx = m0 + mw + 16 * i + rw;
                const int n_idx = n0 + nw + 16 * j + quad * 4;
                float4 vv = { acc[i][j][0], acc[i][j][1], acc[i][j][2], acc[i][j][3] };
                *(float4*)&((float*)C0)[(size_t)m_idx * N + n_idx] = vv;
            }
    } else if (!kvhalf) {
        // q|u: lane -> m(l-row) = +rw; regs -> 4 consecutive n(e)
        #pragma unroll
        for (int i = 0; i < 4; i++)
            #pragma unroll
            for (int j = 0; j < 4; j++) {
                const int m_idx = m0 + mw + 16 * i + rw;
                const int n_idx = n0 + nw + 16 * j + quad * 4;
                int sel = n_idx >> 10, e = n_idx & 1023;
                int b = m_idx >> 12, l = m_idx & 4095, h = e >> 6, hd = e & 63;
                f16x4 o;
                #pragma unroll
                for (int r = 0; r < 4; r++) {
                    float v = acc[i][j][r];
                    o[r] = (f16)(sel ? (v / (1.0f + __expf(-v))) : (fmaxf(v, 0.0f) * 0.125f));
                }
                *(f16x4*)&((f16*)C0)[(size_t)sel * MROWS * EMB +
                                     (((size_t)(b * 16 + h) * 4096 + l) << 6) + hd] = o;
            }
    } else {
        // kT|vT: lane -> n(e) = +rw; regs -> 4 consecutive m(l)
        #pragma unroll
        for (int i = 0; i < 4; i++)
            #pragma unroll
            for (int j = 0; j < 4; j++) {
                const int n_idx = n0 + nw + 16 * j + rw - 2048;
                const int m_idx = m0 + mw + 16 * i + quad * 4;
                int sel = n_idx >> 10, e = n_idx & 1023;
                int b = m_idx >> 12, l = m_idx & 4095;
                f16x4 o;
                #pragma unroll
                for (int r = 0; r < 4; r++) {
                    float v = acc[i][j][r];
                    o[r] = (f16)(sel ? v : (fmaxf(v, 0.0f) * 0.125f));
                }
                *(f16x4*)&((f16*)Ckv)[(size_t)sel * MROWS * EMB +
                                      (((size_t)b * 1024 + e) << 12) + l] = o;
            }
    }
}

// ---------------- split-K kv: kv[m][n] += sum_{l in chunk} k[l][m]*v[l][n] ----------------
__global__ __launch_bounds__(256) void kv_split_kernel(
    const f16* __restrict__ kT, const f16* __restrict__ vT, float* __restrict__ kv32)
{
    const int bh    = blockIdx.x;
    const int chunk = blockIdx.y;
    const int lane  = threadIdx.x & 63;
    const int w     = threadIdx.x >> 6;
    const int rw    = lane & 15;
    const int quad  = lane >> 4;
    const int lbase = chunk * (SEQL / KVSPLIT);

    const f16* kp = kT + (size_t)bh * HD * SEQL + (size_t)(w * 16 + rw) * SEQL + lbase + quad * 8;
    const f16* vp = vT + (size_t)bh * HD * SEQL + (size_t)rw * SEQL + lbase + quad * 8;

    f32x4 acc[4] = {};
    for (int k0 = 0; k0 < SEQL / KVSPLIT; k0 += 32) {
        f16x8 a = *(const f16x8*)(kp + k0);
        #pragma unroll
        for (int t = 0; t < 4; t++) {
            f16x8 b = *(const f16x8*)(vp + (size_t)16 * t * SEQL + k0);
            acc[t] = __builtin_amdgcn_mfma_f32_16x16x32_f16(a, b, acc[t], 0, 0, 0);
        }
    }
    float* out = kv32 + (size_t)bh * HD * HD;
    #pragma unroll
    for (int t = 0; t < 4; t++)
        #pragma unroll
        for (int r = 0; r < 4; r++)
            atomicAdd(&out[(w * 16 + quad * 4 + r) * 64 + t * 16 + rw], acc[t][r]);
}

// ---------------- out = SRMSNorm(q @ kv) * u, written to (b,l,emb) f16 ----------------
__global__ __launch_bounds__(256) void ret_out_kernel(
    const f16* __restrict__ q, const f16* __restrict__ u,
    const float* __restrict__ kv32, f16* __restrict__ o)
{
    const int bh    = blockIdx.x;
    const int chunk = blockIdx.y;
    const int lane  = threadIdx.x & 63;
    const int w     = threadIdx.x >> 6;
    const int rw    = lane & 15;
    const int quad  = lane >> 4;

    const float* kvp = kv32 + (size_t)bh * 4096;
    f16x8 bf[2][4];
    #pragma unroll
    for (int s = 0; s < 2; s++)
        #pragma unroll
        for (int t = 0; t < 4; t++)
            #pragma unroll
            for (int j = 0; j < 8; j++)
                bf[s][t][j] = (f16)kvp[(s * 32 + quad * 8 + j) * 64 + t * 16 + rw];

    const f16* qp = q + (size_t)bh * SEQL * HD;
    const f16* up = u + (size_t)bh * SEQL * HD;
    const int b = bh >> 4, h = bh & 15;
    f16* op = o + (size_t)b * SEQL * EMB + h * 64;

    const int l_wave = chunk * 512 + w * 128;
    for (int s = 0; s < 8; s++) {
        const int l0 = l_wave + s * 16;
        f16x8 a0 = *(const f16x8*)(qp + (size_t)(l0 + rw) * 64 + quad * 8);
        f16x8 a1 = *(const f16x8*)(qp + (size_t)(l0 + rw) * 64 + 32 + quad * 8);
        f32x4 acc[4] = {};
        #pragma unroll
        for (int t = 0; t < 4; t++) {
            acc[t] = __builtin_amdgcn_mfma_f32_16x16x32_f16(a0, bf[0][t], acc[t], 0, 0, 0);
            acc[t] = __builtin_amdgcn_mfma_f32_16x16x32_f16(a1, bf[1][t], acc[t], 0, 0, 0);
        }
        float inv[4];
        #pragma unroll
        for (int r = 0; r < 4; r++) {
            float ss = acc[0][r] * acc[0][r] + acc[1][r] * acc[1][r]
                     + acc[2][r] * acc[2][r] + acc[3][r] * acc[3][r];
            #pragma unroll
            for (int msk = 1; msk < 16; msk <<= 1)
                ss += __shfl_xor(ss, msk, 16);
            inv[r] = 8.0f / fmaxf(sqrtf(ss), 8e-12f);
        }
        #pragma unroll
        for (int t = 0; t < 4; t++)
            #pragma unroll
            for (int r = 0; r < 4; r++) {
                int l = l0 + quad * 4 + r;
                int col = t * 16 + rw;
                float uval = (float)up[(size_t)l * 64 + col];
                op[(size_t)l * EMB + col] = (f16)(acc[t][r] * inv[r] * uval);
            }
    }
}

extern "C" void kernel_launch(void* const* d_in, const int* in_sizes, int n_in,
                              void* d_out, int out_size, void* d_ws, size_t ws_size,
                              hipStream_t stream)
{
    const float* x = (const float*)d_in[0];
    // dst slot order: Wq, Wu, Wk, Wv, Wo  (so [Wq;Wu;Wk;Wv] is one 4096x1024 block)
    WPtrs wp;
    wp.p[0] = (const float*)d_in[1];  // Wq
    wp.p[1] = (const float*)d_in[4];  // Wu
    wp.p[2] = (const float*)d_in[2];  // Wk
    wp.p[3] = (const float*)d_in[3];  // Wv
    wp.p[4] = (const float*)d_in[5];  // Wo

    char* ws = (char*)d_ws;
    size_t off = 0;
    f16* x16 = (f16*)(ws + off); off += (size_t)MROWS * EMB * 2;
    f16* w16 = (f16*)(ws + off); off += (size_t)5 * EMB * EMB * 2;
    f16* qb  = (f16*)(ws + off); off += (size_t)MROWS * EMB * 2;   // q
    f16* ub  = (f16*)(ws + off); off += (size_t)MROWS * EMB * 2;   // u (contiguous after q)
    f16* kTb = (f16*)(ws + off); off += (size_t)MROWS * EMB * 2;   // kT
    f16* vTb = (f16*)(ws + off); off += (size_t)MROWS * EMB * 2;   // vT (contiguous after kT)
    float* kv32 = (float*)(ws + off); off += (size_t)BH * HD * HD * 4;
    f16* ob  = x16;  // reuse: x16 dead after the projection GEMM
    (void)ub; (void)vTb;

    // converts + kv zero-init
    cvt_kernel<<<(MROWS * EMB / 4) / 256, 256, 0, stream>>>(x, x16, MROWS * EMB / 4);
    cvt_w_kernel<<<dim3((EMB * EMB / 4) / 256, 5), 256, 0, stream>>>(wp, w16);
    zero_kernel<<<(BH * HD * HD / 4 + 255) / 256, 256, 0, stream>>>((float4*)kv32, BH * HD * HD / 4);

    f16* Wqukv = w16;                            // [Wq;Wu;Wk;Wv]  4096 x 1024
    f16* Wo    = w16 + (size_t)4 * EMB * EMB;

    dim3 blk(256);
    // all four projections in one dispatch
    gemmw_kernel<1><<<dim3(128 * 32), blk, 0, stream>>>(x16, Wqukv, qb, kTb, MROWS, 4 * EMB, EMB);

    // retention core
    kv_split_kernel<<<dim3(BH, KVSPLIT), blk, 0, stream>>>(kTb, vTb, kv32);
    ret_out_kernel<<<dim3(BH, 8), blk, 0, stream>>>(qb, ub, kv32, ob);

    // final: out = o @ Wo^T, fp32
    gemmw_kernel<0><<<dim3(128 * 8), blk, 0, stream>>>(ob, Wo, d_out, nullptr, MROWS, EMB, EMB);
}